// Round 2
// baseline (2483.633 us; speedup 1.0000x reference)
//
#include <hip/hip_runtime.h>
#include <cstdint>

#define NN 50000
#define NE 512000

typedef unsigned short bf16u;

__device__ __forceinline__ bf16u f2bf(float f){
  union { float f; unsigned int u; } v; v.f = f;
  unsigned int r = v.u + 0x7FFFu + ((v.u >> 16) & 1u);
  return (bf16u)(r >> 16);
}
__device__ __forceinline__ float bf2f(bf16u s){
  union { unsigned int u; float f; } v; v.u = ((unsigned int)s) << 16;
  return v.f;
}

// ---------- K0: weight transposes ----------
// WtE[k*128+o] = E_w[o*64+k]          (64 x 128, k-major)
// W2t[o*64+j]  = ffn2_w[j*128+o]      (128 x 64, o-major)
__global__ void k0_transpose(const float* __restrict__ E_w, const float* __restrict__ ffn2_w,
                             float* __restrict__ WtE, float* __restrict__ W2t){
  int i = blockIdx.x * 256 + threadIdx.x;
  if (i < 64 * 128) { int k = i >> 7, o = i & 127; WtE[i] = E_w[o * 64 + k]; }
  if (i < 128 * 64) { int o = i >> 6, j = i & 63;  W2t[i] = ffn2_w[j * 128 + o]; }
}

// ---------- K1: node QKV (lane = node) ----------
__global__ __launch_bounds__(256) void k1_qkv(const float* __restrict__ x,
    const float* __restrict__ qkv_w, const float* __restrict__ qkv_b,
    float* __restrict__ Q, float* __restrict__ K, float* __restrict__ V){
  int node = blockIdx.x * 256 + threadIdx.x;
  if (node >= NN) return;
  float xr[64];
  const float4* xp = (const float4*)(x + (size_t)node * 64);
#pragma unroll
  for (int c = 0; c < 16; ++c){
    float4 t = xp[c];
    xr[c*4+0]=t.x; xr[c*4+1]=t.y; xr[c*4+2]=t.z; xr[c*4+3]=t.w;
  }
  float* outs[3] = {Q, K, V};
#pragma unroll
  for (int p = 0; p < 3; ++p){
    float* op = outs[p] + (size_t)node * 64;
    for (int o4 = 0; o4 < 16; ++o4){           // runtime loop, uniform
      float r[4];
#pragma unroll
      for (int j = 0; j < 4; ++j){
        int o = p * 64 + o4 * 4 + j;
        const float* wr = qkv_w + (size_t)o * 64;
        float a = qkv_b[o];
#pragma unroll
        for (int k = 0; k < 64; ++k) a += xr[k] * wr[k];
        r[j] = a;
      }
      float4 st = {r[0], r[1], r[2], r[3]};
      *(float4*)(op + o4 * 4) = st;
    }
  }
}

// ---------- K2: edge pass 1 (lane = edge) ----------
// Eh = e @ E_w^T + E_b ; conn_pre = relu(sign((Qd+Ks)*Ew)*sqrt(|..|) + Eb)
// score->exp->atomic ssum ; conn_mid = conn_pre @ conn1_w^T + conn1_b (bf16)
__global__ __launch_bounds__(256) void k2_edge1(
    const float* __restrict__ e, const int* __restrict__ dst, const int* __restrict__ src,
    const float* __restrict__ WtE, const float* __restrict__ E_b,
    const float* __restrict__ Aw, const float* __restrict__ conn1_w, const float* __restrict__ conn1_b,
    const float* __restrict__ Q, const float* __restrict__ K,
    bf16u* __restrict__ cm, float* __restrict__ sexp, float* __restrict__ ssum){
  int edge = blockIdx.x * 256 + threadIdx.x;   // grid exactly covers NE
  float acc[128];
#pragma unroll
  for (int o = 0; o < 128; ++o) acc[o] = 0.f;
  const float4* ep = (const float4*)(e + (size_t)edge * 64);
  for (int kc = 0; kc < 16; ++kc){             // runtime
    float4 t = ep[kc];
    float ev[4] = {t.x, t.y, t.z, t.w};
    const float* wt = WtE + kc * 4 * 128;      // uniform base
#pragma unroll
    for (int j = 0; j < 4; ++j){
#pragma unroll
      for (int o = 0; o < 128; ++o) acc[o] += ev[j] * wt[j * 128 + o];
    }
  }
  int dn = dst[edge], sn = src[edge];
  float cp[64];
#pragma unroll
  for (int dc = 0; dc < 16; ++dc){
    float4 q4 = *(const float4*)(Q + (size_t)dn * 64 + dc * 4);
    float4 k4 = *(const float4*)(K + (size_t)sn * 64 + dc * 4);
    float qv[4] = {q4.x, q4.y, q4.z, q4.w};
    float kv[4] = {k4.x, k4.y, k4.z, k4.w};
#pragma unroll
    for (int j = 0; j < 4; ++j){
      int d = dc * 4 + j;
      float ew = acc[d]      + E_b[d];
      float eb = acc[64 + d] + E_b[64 + d];
      float c1 = (qv[j] + kv[j]) * ew;
      float c2 = copysignf(sqrtf(fabsf(c1)), c1);
      cp[d] = fmaxf(c2 + eb, 0.f);
    }
  }
  // score per head: sum_d cp[h*16+d] * Aw[d*4+h], clip +-5, exp
  float ex4[4];
#pragma unroll
  for (int h = 0; h < 4; ++h){
    float s = 0.f;
#pragma unroll
    for (int j = 0; j < 16; ++j) s += cp[h * 16 + j] * Aw[j * 4 + h];
    s = fminf(fmaxf(s, -5.f), 5.f);
    ex4[h] = __expf(s);
    atomicAdd(&ssum[(size_t)dn * 4 + h], ex4[h]);
  }
  float4 sx = {ex4[0], ex4[1], ex4[2], ex4[3]};
  *(float4*)(sexp + (size_t)edge * 4) = sx;
  // conn_mid
  for (int o4 = 0; o4 < 16; ++o4){             // runtime
    bf16u r[4];
#pragma unroll
    for (int j = 0; j < 4; ++j){
      int o = o4 * 4 + j;
      const float* wr = conn1_w + (size_t)o * 64;
      float a = conn1_b[o];
#pragma unroll
      for (int k = 0; k < 64; ++k) a += cp[k] * wr[k];
      r[j] = f2bf(a);
    }
    ushort4 st = {r[0], r[1], r[2], r[3]};
    *(ushort4*)(cm + (size_t)edge * 64 + o4 * 4) = st;
  }
}

// ---------- K4: edge pass 2 (lane = edge) ----------
// score = sexp/(ssum[dst]+1e-16); msg atomics into agg;
// conn out = LN2c( relu(LN1c(cm)) @ conn2_w^T + conn2_b + e )   [f32 out]
__global__ __launch_bounds__(256) void k4_edge2(
    const float* __restrict__ e, const int* __restrict__ dst, const int* __restrict__ src,
    const bf16u* __restrict__ cm, const float* __restrict__ sexp, const float* __restrict__ ssum,
    const float* __restrict__ V,
    const float* __restrict__ g1c, const float* __restrict__ b1c,
    const float* __restrict__ conn2_w, const float* __restrict__ conn2_b,
    const float* __restrict__ g2c, const float* __restrict__ b2c,
    float* __restrict__ agg, float* __restrict__ out_conn){
  int edge = blockIdx.x * 256 + threadIdx.x;
  int dn = dst[edge], sn = src[edge];
  float c[64];
  const ushort4* cp4 = (const ushort4*)(cm + (size_t)edge * 64);
#pragma unroll
  for (int q = 0; q < 16; ++q){
    ushort4 t = cp4[q];
    c[q*4+0] = bf2f(t.x); c[q*4+1] = bf2f(t.y); c[q*4+2] = bf2f(t.z); c[q*4+3] = bf2f(t.w);
  }
  float4 sx = *(const float4*)(sexp + (size_t)edge * 4);
  float4 sv = *(const float4*)(ssum + (size_t)dn * 4);
  float sc[4] = { sx.x / (sv.x + 1e-16f), sx.y / (sv.y + 1e-16f),
                  sx.z / (sv.z + 1e-16f), sx.w / (sv.w + 1e-16f) };
  // message aggregation (atomics)
#pragma unroll
  for (int dc = 0; dc < 16; ++dc){
    float4 v4 = *(const float4*)(V + (size_t)sn * 64 + dc * 4);
    float vv[4] = {v4.x, v4.y, v4.z, v4.w};
#pragma unroll
    for (int j = 0; j < 4; ++j){
      int d = dc * 4 + j;
      float m = (vv[j] + c[d]) * sc[d >> 4];
      atomicAdd(&agg[(size_t)dn * 64 + d], m);
    }
  }
  // LN1c + relu
  float mu = 0.f;
#pragma unroll
  for (int d = 0; d < 64; ++d) mu += c[d];
  mu *= (1.f / 64.f);
  float var = 0.f;
#pragma unroll
  for (int d = 0; d < 64; ++d){ float t = c[d] - mu; var += t * t; }
  var *= (1.f / 64.f);
  float rs = rsqrtf(var + 1e-5f);
  float cl[64];
#pragma unroll
  for (int d = 0; d < 64; ++d) cl[d] = fmaxf((c[d] - mu) * rs * g1c[d] + b1c[d], 0.f);
  // conn2 GEMV pass 1: stats of r = cl@W2c^T + b + e
  float sum = 0.f, sq = 0.f;
  for (int o4 = 0; o4 < 16; ++o4){             // runtime
    float4 e4 = *(const float4*)(e + (size_t)edge * 64 + o4 * 4);
    float evv[4] = {e4.x, e4.y, e4.z, e4.w};
#pragma unroll
    for (int j = 0; j < 4; ++j){
      int o = o4 * 4 + j;
      const float* wr = conn2_w + (size_t)o * 64;
      float a = conn2_b[o];
#pragma unroll
      for (int k = 0; k < 64; ++k) a += cl[k] * wr[k];
      float r = a + evv[j];
      sum += r; sq += r * r;
    }
  }
  float mu2 = sum * (1.f / 64.f);
  float var2 = sq * (1.f / 64.f) - mu2 * mu2;
  float rs2 = rsqrtf(fmaxf(var2, 0.f) + 1e-5f);
  // pass 2: recompute r, normalize, store f32
  for (int o4 = 0; o4 < 16; ++o4){             // runtime
    float4 e4 = *(const float4*)(e + (size_t)edge * 64 + o4 * 4);
    float evv[4] = {e4.x, e4.y, e4.z, e4.w};
    float rb[4];
#pragma unroll
    for (int j = 0; j < 4; ++j){
      int o = o4 * 4 + j;
      const float* wr = conn2_w + (size_t)o * 64;
      float a = conn2_b[o];
#pragma unroll
      for (int k = 0; k < 64; ++k) a += cl[k] * wr[k];
      float r = a + evv[j];
      rb[j] = (r - mu2) * rs2 * g2c[o] + b2c[o];
    }
    float4 st = {rb[0], rb[1], rb[2], rb[3]};
    *(float4*)(out_conn + (size_t)edge * 64 + o4 * 4) = st;
  }
}

// ---------- K5: node final (lane = node) ----------
// h = x + agg; LN1h; FFN (relu); LN2h(ffn + h_res)   [f32 out]
__global__ __launch_bounds__(256) void k5_node(
    const float* __restrict__ x, const float* __restrict__ agg,
    const float* __restrict__ g1, const float* __restrict__ b1,
    const float* __restrict__ ffn1_w, const float* __restrict__ ffn1_b,
    const float* __restrict__ W2t, const float* __restrict__ ffn2_b,
    const float* __restrict__ g2, const float* __restrict__ b2,
    float* __restrict__ out_h){
  int node = blockIdx.x * 256 + threadIdx.x;
  if (node >= NN) return;
  float hr[64];
  const float4* xp = (const float4*)(x + (size_t)node * 64);
  const float4* ap = (const float4*)(agg + (size_t)node * 64);
#pragma unroll
  for (int q = 0; q < 16; ++q){
    float4 xv = xp[q], av = ap[q];
    hr[q*4+0]=xv.x+av.x; hr[q*4+1]=xv.y+av.y; hr[q*4+2]=xv.z+av.z; hr[q*4+3]=xv.w+av.w;
  }
  float mu = 0.f;
#pragma unroll
  for (int d = 0; d < 64; ++d) mu += hr[d];
  mu *= (1.f / 64.f);
  float var = 0.f;
#pragma unroll
  for (int d = 0; d < 64; ++d){ float t = hr[d] - mu; var += t * t; }
  var *= (1.f / 64.f);
  float rs = rsqrtf(var + 1e-5f);
  float hl[64];
#pragma unroll
  for (int d = 0; d < 64; ++d) hl[d] = (hr[d] - mu) * rs * g1[d] + b1[d];
  float oacc[64];
#pragma unroll
  for (int j = 0; j < 64; ++j) oacc[j] = ffn2_b[j];
  for (int o = 0; o < 128; ++o){               // runtime
    const float* wr = ffn1_w + (size_t)o * 64;
    float a = ffn1_b[o];
#pragma unroll
    for (int k = 0; k < 64; ++k) a += hl[k] * wr[k];
    a = fmaxf(a, 0.f);
    const float* w2 = W2t + (size_t)o * 64;
#pragma unroll
    for (int j = 0; j < 64; ++j) oacc[j] += a * w2[j];
  }
  // LN2h over oacc + hr
#pragma unroll
  for (int j = 0; j < 64; ++j) oacc[j] += hr[j];
  float mu2 = 0.f;
#pragma unroll
  for (int j = 0; j < 64; ++j) mu2 += oacc[j];
  mu2 *= (1.f / 64.f);
  float var2 = 0.f;
#pragma unroll
  for (int j = 0; j < 64; ++j){ float t = oacc[j] - mu2; var2 += t * t; }
  var2 *= (1.f / 64.f);
  float rs2 = rsqrtf(var2 + 1e-5f);
#pragma unroll
  for (int q = 0; q < 16; ++q){
    float rb[4];
#pragma unroll
    for (int j = 0; j < 4; ++j){
      int d = q * 4 + j;
      rb[j] = (oacc[d] - mu2) * rs2 * g2[d] + b2[d];
    }
    float4 st = {rb[0], rb[1], rb[2], rb[3]};
    *(float4*)(out_h + (size_t)node * 64 + q * 4) = st;
  }
}

extern "C" void kernel_launch(void* const* d_in, const int* in_sizes, int n_in,
                              void* d_out, int out_size, void* d_ws, size_t ws_size,
                              hipStream_t stream){
  const float* x       = (const float*)d_in[0];
  const float* e       = (const float*)d_in[1];
  const int*   dst     = (const int*)d_in[2];
  const int*   src     = (const int*)d_in[3];
  const float* qkv_w   = (const float*)d_in[4];
  const float* qkv_b   = (const float*)d_in[5];
  const float* E_w     = (const float*)d_in[6];
  const float* E_b     = (const float*)d_in[7];
  const float* Aw      = (const float*)d_in[8];
  const float* conn1_w = (const float*)d_in[9];
  const float* conn1_b = (const float*)d_in[10];
  const float* conn2_w = (const float*)d_in[11];
  const float* conn2_b = (const float*)d_in[12];
  const float* ffn1_w  = (const float*)d_in[13];
  const float* ffn1_b  = (const float*)d_in[14];
  const float* ffn2_w  = (const float*)d_in[15];
  const float* ffn2_b  = (const float*)d_in[16];
  const float* ln1h_g  = (const float*)d_in[17];
  const float* ln1h_b  = (const float*)d_in[18];
  const float* ln2h_g  = (const float*)d_in[19];
  const float* ln2h_b  = (const float*)d_in[20];
  const float* ln1c_g  = (const float*)d_in[21];
  const float* ln1c_b  = (const float*)d_in[22];
  const float* ln2c_g  = (const float*)d_in[23];
  const float* ln2c_b  = (const float*)d_in[24];

  char* ws = (char*)d_ws;
  size_t off = 0;
  auto alloc = [&](size_t bytes) -> void* {
    void* p = ws + off;
    off += (bytes + 255) & ~(size_t)255;
    return p;
  };
  float* Q    = (float*)alloc((size_t)NN * 64 * 4);
  float* Kq   = (float*)alloc((size_t)NN * 64 * 4);
  float* V    = (float*)alloc((size_t)NN * 64 * 4);
  bf16u* cmb  = (bf16u*)alloc((size_t)NE * 64 * 2);
  float* sexp = (float*)alloc((size_t)NE * 4 * 4);
  float* ssum = (float*)alloc((size_t)NN * 4 * 4);
  float* agg  = (float*)alloc((size_t)NN * 64 * 4);
  float* WtE  = (float*)alloc(64 * 128 * 4);
  float* W2t  = (float*)alloc(128 * 64 * 4);

  float* out_h    = (float*)d_out;
  float* out_conn = out_h + (size_t)NN * 64;

  hipMemsetAsync(ssum, 0, (size_t)NN * 16, stream);
  hipMemsetAsync(agg,  0, (size_t)NN * 64 * 4, stream);

  k0_transpose<<<32, 256, 0, stream>>>(E_w, ffn2_w, WtE, W2t);
  k1_qkv<<<(NN + 255) / 256, 256, 0, stream>>>(x, qkv_w, qkv_b, Q, Kq, V);
  k2_edge1<<<NE / 256, 256, 0, stream>>>(e, dst, src, WtE, E_b, Aw, conn1_w, conn1_b,
                                         Q, Kq, cmb, sexp, ssum);
  k4_edge2<<<NE / 256, 256, 0, stream>>>(e, dst, src, cmb, sexp, ssum, V,
                                         ln1c_g, ln1c_b, conn2_w, conn2_b, ln2c_g, ln2c_b,
                                         agg, out_conn);
  k5_node<<<(NN + 255) / 256, 256, 0, stream>>>(x, agg, ln1h_g, ln1h_b, ffn1_w, ffn1_b,
                                                W2t, ffn2_b, ln2h_g, ln2h_b, out_h);
}

// Round 3
// 1222.284 us; speedup vs baseline: 2.0320x; 2.0320x over previous
//
#include <hip/hip_runtime.h>
#include <cstdint>

#define NN 50000
#define NE 512000

typedef unsigned short bf16u;

__device__ __forceinline__ bf16u f2bf(float f){
  union { float f; unsigned int u; } v; v.f = f;
  unsigned int r = v.u + 0x7FFFu + ((v.u >> 16) & 1u);
  return (bf16u)(r >> 16);
}
__device__ __forceinline__ float bf2f(bf16u s){
  union { unsigned int u; float f; } v; v.u = ((unsigned int)s) << 16;
  return v.f;
}

// ---------- K0: weight transposes ----------
__global__ void k0_transpose(const float* __restrict__ E_w, const float* __restrict__ ffn2_w,
                             float* __restrict__ WtE, float* __restrict__ W2t){
  int i = blockIdx.x * 256 + threadIdx.x;
  if (i < 64 * 128) { int k = i >> 7, o = i & 127; WtE[i] = E_w[o * 64 + k]; }
  if (i < 128 * 64) { int o = i >> 6, j = i & 63;  W2t[i] = ffn2_w[j * 128 + o]; }
}

// ---------- CSR build ----------
__global__ void k_hist(const int* __restrict__ dst, int* __restrict__ cnt){
  int e = blockIdx.x * 256 + threadIdx.x;
  if (e < NE) atomicAdd(&cnt[dst[e]], 1);
}

#define SCAN_T 1024
#define PER_T 49   // 1024*49 = 50176 >= NN
__global__ __launch_bounds__(SCAN_T) void k_scan(const int* __restrict__ cnt, int* __restrict__ start){
  __shared__ int ls[SCAN_T];
  int t = threadIdx.x;
  int base = t * PER_T;
  int s = 0;
  for (int i = 0; i < PER_T; ++i){ int n = base + i; if (n < NN) s += cnt[n]; }
  ls[t] = s; __syncthreads();
  for (int off = 1; off < SCAN_T; off <<= 1){
    int v = ls[t];
    int add = (t >= off) ? ls[t - off] : 0;
    __syncthreads();
    ls[t] = v + add;
    __syncthreads();
  }
  int run = (t > 0) ? ls[t - 1] : 0;
  for (int i = 0; i < PER_T; ++i){
    int n = base + i;
    if (n < NN){ start[n] = run; run += cnt[n]; }
  }
  if (t == SCAN_T - 1) start[NN] = run;   // == NE
}

__global__ void k_scatter(const int* __restrict__ dst, int* __restrict__ cursor, int* __restrict__ eidx){
  int e = blockIdx.x * 256 + threadIdx.x;
  if (e < NE){ int p = atomicAdd(&cursor[dst[e]], 1); eidx[p] = e; }
}

// ---------- K1: node QKV (lane = node) ----------
__global__ __launch_bounds__(256) void k1_qkv(const float* __restrict__ x,
    const float* __restrict__ qkv_w, const float* __restrict__ qkv_b,
    float* __restrict__ Q, float* __restrict__ K, float* __restrict__ V){
  int node = blockIdx.x * 256 + threadIdx.x;
  if (node >= NN) return;
  float xr[64];
  const float4* xp = (const float4*)(x + (size_t)node * 64);
#pragma unroll
  for (int c = 0; c < 16; ++c){
    float4 t = xp[c];
    xr[c*4+0]=t.x; xr[c*4+1]=t.y; xr[c*4+2]=t.z; xr[c*4+3]=t.w;
  }
  float* outs[3] = {Q, K, V};
#pragma unroll
  for (int p = 0; p < 3; ++p){
    float* op = outs[p] + (size_t)node * 64;
    for (int o4 = 0; o4 < 16; ++o4){
      float r[4];
#pragma unroll
      for (int j = 0; j < 4; ++j){
        int o = p * 64 + o4 * 4 + j;
        const float* wr = qkv_w + (size_t)o * 64;
        float a = qkv_b[o];
#pragma unroll
        for (int k = 0; k < 64; ++k) a += xr[k] * wr[k];
        r[j] = a;
      }
      float4 st = {r[0], r[1], r[2], r[3]};
      *(float4*)(op + o4 * 4) = st;
    }
  }
}

// ---------- K2: edge pass 1 (lane = edge) — no atomics ----------
__global__ __launch_bounds__(256) void k2_edge1(
    const float* __restrict__ e, const int* __restrict__ dst, const int* __restrict__ src,
    const float* __restrict__ WtE, const float* __restrict__ E_b,
    const float* __restrict__ Aw, const float* __restrict__ conn1_w, const float* __restrict__ conn1_b,
    const float* __restrict__ Q, const float* __restrict__ K,
    bf16u* __restrict__ cm, float* __restrict__ sexp){
  int edge = blockIdx.x * 256 + threadIdx.x;
  float acc[128];
#pragma unroll
  for (int o = 0; o < 128; ++o) acc[o] = 0.f;
  const float4* ep = (const float4*)(e + (size_t)edge * 64);
  for (int kc = 0; kc < 16; ++kc){
    float4 t = ep[kc];
    float ev[4] = {t.x, t.y, t.z, t.w};
    const float* wt = WtE + kc * 4 * 128;
#pragma unroll
    for (int j = 0; j < 4; ++j){
#pragma unroll
      for (int o = 0; o < 128; ++o) acc[o] += ev[j] * wt[j * 128 + o];
    }
  }
  int dn = dst[edge], sn = src[edge];
  float cp[64];
#pragma unroll
  for (int dc = 0; dc < 16; ++dc){
    float4 q4 = *(const float4*)(Q + (size_t)dn * 64 + dc * 4);
    float4 k4 = *(const float4*)(K + (size_t)sn * 64 + dc * 4);
    float qv[4] = {q4.x, q4.y, q4.z, q4.w};
    float kv[4] = {k4.x, k4.y, k4.z, k4.w};
#pragma unroll
    for (int j = 0; j < 4; ++j){
      int d = dc * 4 + j;
      float ew = acc[d]      + E_b[d];
      float eb = acc[64 + d] + E_b[64 + d];
      float c1 = (qv[j] + kv[j]) * ew;
      float c2 = copysignf(sqrtf(fabsf(c1)), c1);
      cp[d] = fmaxf(c2 + eb, 0.f);
    }
  }
  float ex4[4];
#pragma unroll
  for (int h = 0; h < 4; ++h){
    float s = 0.f;
#pragma unroll
    for (int j = 0; j < 16; ++j) s += cp[h * 16 + j] * Aw[j * 4 + h];
    s = fminf(fmaxf(s, -5.f), 5.f);
    ex4[h] = __expf(s);
  }
  float4 sx = {ex4[0], ex4[1], ex4[2], ex4[3]};
  *(float4*)(sexp + (size_t)edge * 4) = sx;
  for (int o4 = 0; o4 < 16; ++o4){
    bf16u r[4];
#pragma unroll
    for (int j = 0; j < 4; ++j){
      int o = o4 * 4 + j;
      const float* wr = conn1_w + (size_t)o * 64;
      float a = conn1_b[o];
#pragma unroll
      for (int k = 0; k < 64; ++k) a += cp[k] * wr[k];
      r[j] = f2bf(a);
    }
    ushort4 st = {r[0], r[1], r[2], r[3]};
    *(ushort4*)(cm + (size_t)edge * 64 + o4 * 4) = st;
  }
}

// ---------- K_agg: wave per node, CSR gather (no atomics) ----------
// hpre = x + sum_edges (V[src]+cm[e]) * sexp[e,h]/(sum sexp + 1e-16)
__global__ __launch_bounds__(256) void k_agg(
    const int* __restrict__ start, const int* __restrict__ eidx, const int* __restrict__ srcv,
    const float* __restrict__ sexp, const bf16u* __restrict__ cm, const float* __restrict__ V,
    const float* __restrict__ x, float* __restrict__ hpre){
  int wid = (blockIdx.x * 256 + threadIdx.x) >> 6;
  int lane = threadIdx.x & 63;
  if (wid >= NN) return;
  int s0 = start[wid], s1 = start[wid + 1];
  int h = lane >> 4;
  float ssum = 0.f;
  for (int i = s0; i < s1; ++i){
    int eid = eidx[i];
    ssum += sexp[(size_t)eid * 4 + h];
  }
  float inv = 1.f / (ssum + 1e-16f);
  float acc = 0.f;
  for (int i = s0; i < s1; ++i){
    int eid = eidx[i];
    int sn = srcv[eid];
    float sc = sexp[(size_t)eid * 4 + h] * inv;
    float v  = V[(size_t)sn * 64 + lane];
    float cc = bf2f(cm[(size_t)eid * 64 + lane]);
    acc += (v + cc) * sc;
  }
  hpre[(size_t)wid * 64 + lane] = x[(size_t)wid * 64 + lane] + acc;
}

// ---------- K4: conn path only (lane = edge) ----------
__global__ __launch_bounds__(256) void k4_conn(
    const float* __restrict__ e, const bf16u* __restrict__ cm,
    const float* __restrict__ g1c, const float* __restrict__ b1c,
    const float* __restrict__ conn2_w, const float* __restrict__ conn2_b,
    const float* __restrict__ g2c, const float* __restrict__ b2c,
    float* __restrict__ out_conn){
  int edge = blockIdx.x * 256 + threadIdx.x;
  float c[64];
  const ushort4* cp4 = (const ushort4*)(cm + (size_t)edge * 64);
#pragma unroll
  for (int q = 0; q < 16; ++q){
    ushort4 t = cp4[q];
    c[q*4+0] = bf2f(t.x); c[q*4+1] = bf2f(t.y); c[q*4+2] = bf2f(t.z); c[q*4+3] = bf2f(t.w);
  }
  float mu = 0.f;
#pragma unroll
  for (int d = 0; d < 64; ++d) mu += c[d];
  mu *= (1.f / 64.f);
  float var = 0.f;
#pragma unroll
  for (int d = 0; d < 64; ++d){ float t = c[d] - mu; var += t * t; }
  var *= (1.f / 64.f);
  float rs = rsqrtf(var + 1e-5f);
  float cl[64];
#pragma unroll
  for (int d = 0; d < 64; ++d) cl[d] = fmaxf((c[d] - mu) * rs * g1c[d] + b1c[d], 0.f);
  float sum = 0.f, sq = 0.f;
  for (int o4 = 0; o4 < 16; ++o4){
    float4 e4 = *(const float4*)(e + (size_t)edge * 64 + o4 * 4);
    float evv[4] = {e4.x, e4.y, e4.z, e4.w};
#pragma unroll
    for (int j = 0; j < 4; ++j){
      int o = o4 * 4 + j;
      const float* wr = conn2_w + (size_t)o * 64;
      float a = conn2_b[o];
#pragma unroll
      for (int k = 0; k < 64; ++k) a += cl[k] * wr[k];
      float r = a + evv[j];
      sum += r; sq += r * r;
    }
  }
  float mu2 = sum * (1.f / 64.f);
  float var2 = sq * (1.f / 64.f) - mu2 * mu2;
  float rs2 = rsqrtf(fmaxf(var2, 0.f) + 1e-5f);
  for (int o4 = 0; o4 < 16; ++o4){
    float4 e4 = *(const float4*)(e + (size_t)edge * 64 + o4 * 4);
    float evv[4] = {e4.x, e4.y, e4.z, e4.w};
    float rb[4];
#pragma unroll
    for (int j = 0; j < 4; ++j){
      int o = o4 * 4 + j;
      const float* wr = conn2_w + (size_t)o * 64;
      float a = conn2_b[o];
#pragma unroll
      for (int k = 0; k < 64; ++k) a += cl[k] * wr[k];
      float r = a + evv[j];
      rb[j] = (r - mu2) * rs2 * g2c[o] + b2c[o];
    }
    float4 st = {rb[0], rb[1], rb[2], rb[3]};
    *(float4*)(out_conn + (size_t)edge * 64 + o4 * 4) = st;
  }
}

// ---------- K5: node final (lane = node), reads hpre ----------
__global__ __launch_bounds__(256) void k5_node(
    const float* __restrict__ hpre,
    const float* __restrict__ g1, const float* __restrict__ b1,
    const float* __restrict__ ffn1_w, const float* __restrict__ ffn1_b,
    const float* __restrict__ W2t, const float* __restrict__ ffn2_b,
    const float* __restrict__ g2, const float* __restrict__ b2,
    float* __restrict__ out_h){
  int node = blockIdx.x * 256 + threadIdx.x;
  if (node >= NN) return;
  float hr[64];
  const float4* hp = (const float4*)(hpre + (size_t)node * 64);
#pragma unroll
  for (int q = 0; q < 16; ++q){
    float4 t = hp[q];
    hr[q*4+0]=t.x; hr[q*4+1]=t.y; hr[q*4+2]=t.z; hr[q*4+3]=t.w;
  }
  float mu = 0.f;
#pragma unroll
  for (int d = 0; d < 64; ++d) mu += hr[d];
  mu *= (1.f / 64.f);
  float var = 0.f;
#pragma unroll
  for (int d = 0; d < 64; ++d){ float t = hr[d] - mu; var += t * t; }
  var *= (1.f / 64.f);
  float rs = rsqrtf(var + 1e-5f);
  float hl[64];
#pragma unroll
  for (int d = 0; d < 64; ++d) hl[d] = (hr[d] - mu) * rs * g1[d] + b1[d];
  float oacc[64];
#pragma unroll
  for (int j = 0; j < 64; ++j) oacc[j] = ffn2_b[j];
  for (int o = 0; o < 128; ++o){
    const float* wr = ffn1_w + (size_t)o * 64;
    float a = ffn1_b[o];
#pragma unroll
    for (int k = 0; k < 64; ++k) a += hl[k] * wr[k];
    a = fmaxf(a, 0.f);
    const float* w2 = W2t + (size_t)o * 64;
#pragma unroll
    for (int j = 0; j < 64; ++j) oacc[j] += a * w2[j];
  }
#pragma unroll
  for (int j = 0; j < 64; ++j) oacc[j] += hr[j];
  float mu2 = 0.f;
#pragma unroll
  for (int j = 0; j < 64; ++j) mu2 += oacc[j];
  mu2 *= (1.f / 64.f);
  float var2 = 0.f;
#pragma unroll
  for (int j = 0; j < 64; ++j){ float t = oacc[j] - mu2; var2 += t * t; }
  var2 *= (1.f / 64.f);
  float rs2 = rsqrtf(var2 + 1e-5f);
#pragma unroll
  for (int q = 0; q < 16; ++q){
    float rb[4];
#pragma unroll
    for (int j = 0; j < 4; ++j){
      int d = q * 4 + j;
      rb[j] = (oacc[d] - mu2) * rs2 * g2[d] + b2[d];
    }
    float4 st = {rb[0], rb[1], rb[2], rb[3]};
    *(float4*)(out_h + (size_t)node * 64 + q * 4) = st;
  }
}

extern "C" void kernel_launch(void* const* d_in, const int* in_sizes, int n_in,
                              void* d_out, int out_size, void* d_ws, size_t ws_size,
                              hipStream_t stream){
  const float* x       = (const float*)d_in[0];
  const float* e       = (const float*)d_in[1];
  const int*   dst     = (const int*)d_in[2];
  const int*   src     = (const int*)d_in[3];
  const float* qkv_w   = (const float*)d_in[4];
  const float* qkv_b   = (const float*)d_in[5];
  const float* E_w     = (const float*)d_in[6];
  const float* E_b     = (const float*)d_in[7];
  const float* Aw      = (const float*)d_in[8];
  const float* conn1_w = (const float*)d_in[9];
  const float* conn1_b = (const float*)d_in[10];
  const float* conn2_w = (const float*)d_in[11];
  const float* conn2_b = (const float*)d_in[12];
  const float* ffn1_w  = (const float*)d_in[13];
  const float* ffn1_b  = (const float*)d_in[14];
  const float* ffn2_w  = (const float*)d_in[15];
  const float* ffn2_b  = (const float*)d_in[16];
  const float* ln1h_g  = (const float*)d_in[17];
  const float* ln1h_b  = (const float*)d_in[18];
  const float* ln2h_g  = (const float*)d_in[19];
  const float* ln2h_b  = (const float*)d_in[20];
  const float* ln1c_g  = (const float*)d_in[21];
  const float* ln1c_b  = (const float*)d_in[22];
  const float* ln2c_g  = (const float*)d_in[23];
  const float* ln2c_b  = (const float*)d_in[24];

  char* ws = (char*)d_ws;
  size_t off = 0;
  auto alloc = [&](size_t bytes) -> void* {
    void* p = ws + off;
    off += (bytes + 255) & ~(size_t)255;
    return p;
  };
  float* Q     = (float*)alloc((size_t)NN * 64 * 4);
  float* Kq    = (float*)alloc((size_t)NN * 64 * 4);
  float* V     = (float*)alloc((size_t)NN * 64 * 4);
  bf16u* cmb   = (bf16u*)alloc((size_t)NE * 64 * 2);
  float* sexp  = (float*)alloc((size_t)NE * 4 * 4);
  float* hpre  = (float*)alloc((size_t)NN * 64 * 4);
  float* WtE   = (float*)alloc(64 * 128 * 4);
  float* W2t   = (float*)alloc(128 * 64 * 4);
  int*   cnt   = (int*)alloc((size_t)NN * 4);
  int*   startp= (int*)alloc(((size_t)NN + 1) * 4);
  int*   cursor= (int*)alloc((size_t)NN * 4);
  int*   eidx  = (int*)alloc((size_t)NE * 4);

  float* out_h    = (float*)d_out;
  float* out_conn = out_h + (size_t)NN * 64;

  hipMemsetAsync(cnt, 0, (size_t)NN * 4, stream);

  k0_transpose<<<32, 256, 0, stream>>>(E_w, ffn2_w, WtE, W2t);
  k_hist<<<NE / 256, 256, 0, stream>>>(dst, cnt);
  k_scan<<<1, SCAN_T, 0, stream>>>(cnt, startp);
  hipMemcpyAsync(cursor, startp, (size_t)NN * 4, hipMemcpyDeviceToDevice, stream);
  k_scatter<<<NE / 256, 256, 0, stream>>>(dst, cursor, eidx);
  k1_qkv<<<(NN + 255) / 256, 256, 0, stream>>>(x, qkv_w, qkv_b, Q, Kq, V);
  k2_edge1<<<NE / 256, 256, 0, stream>>>(e, dst, src, WtE, E_b, Aw, conn1_w, conn1_b,
                                         Q, Kq, cmb, sexp);
  k_agg<<<(NN * 64 + 255) / 256, 256, 0, stream>>>(startp, eidx, src, sexp, cmb, V, x, hpre);
  k4_conn<<<NE / 256, 256, 0, stream>>>(e, cmb, ln1c_g, ln1c_b, conn2_w, conn2_b,
                                        ln2c_g, ln2c_b, out_conn);
  k5_node<<<(NN + 255) / 256, 256, 0, stream>>>(hpre, ln1h_g, ln1h_b, ffn1_w, ffn1_b,
                                                W2t, ffn2_b, ln2h_g, ln2h_b, out_h);
}